// Round 1
// baseline (3221.335 us; speedup 1.0000x reference)
//
#include <hip/hip_runtime.h>

// Pair scatter-add: potential[i] += charges[j]*w, potential[j] += charges[i]*w,
// w = 0.5/d (the 0.5 folds in the reference's final /2). Output fp32.
//
// Baseline: 1 thread/pair, vectorized loads, 8 fp32 atomics/thread.

__global__ __launch_bounds__(256) void pair_scatter_kernel(
    const float4* __restrict__ charges,        // [N_ATOMS] float4 (4 channels)
    const int2*   __restrict__ idx,            // [N_PAIRS] (i, j)
    const float*  __restrict__ dist,           // [N_PAIRS]
    float*        __restrict__ out,            // [N_ATOMS] x 4, zero-initialized
    int npairs)
{
    int t = blockIdx.x * blockDim.x + threadIdx.x;
    if (t >= npairs) return;

    int2  ij = idx[t];
    float w  = 0.5f / dist[t];     // d^(-1) * 1/2

    float4 ci = charges[ij.x];
    float4 cj = charges[ij.y];

    float* oi = out + 4 * (size_t)ij.x;
    float* oj = out + 4 * (size_t)ij.y;

    atomicAdd(oi + 0, cj.x * w);
    atomicAdd(oi + 1, cj.y * w);
    atomicAdd(oi + 2, cj.z * w);
    atomicAdd(oi + 3, cj.w * w);

    atomicAdd(oj + 0, ci.x * w);
    atomicAdd(oj + 1, ci.y * w);
    atomicAdd(oj + 2, ci.z * w);
    atomicAdd(oj + 3, ci.w * w);
}

extern "C" void kernel_launch(void* const* d_in, const int* in_sizes, int n_in,
                              void* d_out, int out_size, void* d_ws, size_t ws_size,
                              hipStream_t stream) {
    const float4* charges = (const float4*)d_in[0];   // (200000, 4) fp32
    const int2*   idx     = (const int2*)  d_in[1];   // (8000000, 2) int32
    const float*  dist    = (const float*) d_in[2];   // (8000000,) fp32
    float*        out     = (float*)d_out;            // (200000, 4) fp32

    const int npairs = in_sizes[2];                   // 8,000,000

    // Harness poisons d_out with 0xAA before every launch — zero it.
    hipMemsetAsync(d_out, 0, (size_t)out_size * sizeof(float), stream);

    const int block = 256;
    const int grid  = (npairs + block - 1) / block;
    pair_scatter_kernel<<<grid, block, 0, stream>>>(charges, idx, dist, out, npairs);
}

// Round 2
// 1071.572 us; speedup vs baseline: 3.0062x; 3.0062x over previous
//
#include <hip/hip_runtime.h>

// Strategy: privatize the 3.2 MB output in LDS chunks.
//   - Atoms split into chunks of CHUNK_ATOMS (8192 -> 128 KiB LDS, C=25).
//   - Grid = C chunks x S slices. Block (c,s) scans pair-slice s, accumulates
//     contributions hitting chunk c via LDS atomicAdd (no global atomics).
//   - USE_WS path: each block writes its chunk to a private ws slab; a second
//     kernel sums the S slabs per chunk (fully streaming, no atomics).
//   - Fallback (small ws): blocks atomicAdd their chunk into d_out (S per addr).
// Baseline was atomic-rate bound: 64M global fp32 atomics, 2 GB write-through.
// This has 0 (ws path) or 8M (fallback) global atomics.

#define BLOCK 1024
#define NSLICES 10

template<int CHUNK_ATOMS, bool USE_WS>
__global__ __launch_bounds__(BLOCK) void chunk_scan(
    const float4* __restrict__ charges,   // [natoms]
    const int2*   __restrict__ idx,       // [npairs]
    const float*  __restrict__ dist,      // [npairs]
    float*        __restrict__ dest,      // ws (slabs) or out
    int npairs, int natoms)
{
    constexpr int CH_ELEMS = CHUNK_ATOMS * 4;
    extern __shared__ float sm[];

    const int c  = blockIdx.x / NSLICES;
    const int s  = blockIdx.x - c * NSLICES;
    const int c0 = c * CHUNK_ATOMS;
    const int cn = min(CHUNK_ATOMS, natoms - c0);   // atoms in this chunk

    for (int e = threadIdx.x; e < CH_ELEMS; e += BLOCK) sm[e] = 0.f;
    __syncthreads();

    const int p0 = (int)((long long)npairs * s       / NSLICES);
    const int p1 = (int)((long long)npairs * (s + 1) / NSLICES);

    for (int p = p0 + threadIdx.x; p < p1; p += BLOCK) {
        int2 ij = idx[p];
        unsigned li = (unsigned)(ij.x - c0);
        unsigned lj = (unsigned)(ij.y - c0);
        bool ini = li < (unsigned)cn;
        bool inj = lj < (unsigned)cn;
        if (ini || inj) {
            float w = 0.5f / dist[p];
            if (ini) {
                float4 cq = charges[ij.y];
                float* b = sm + li * 4;
                atomicAdd(b + 0, cq.x * w);
                atomicAdd(b + 1, cq.y * w);
                atomicAdd(b + 2, cq.z * w);
                atomicAdd(b + 3, cq.w * w);
            }
            if (inj) {
                float4 cq = charges[ij.x];
                float* b = sm + lj * 4;
                atomicAdd(b + 0, cq.x * w);
                atomicAdd(b + 1, cq.y * w);
                atomicAdd(b + 2, cq.z * w);
                atomicAdd(b + 3, cq.w * w);
            }
        }
    }
    __syncthreads();

    const int nvalid = cn * 4;
    if (USE_WS) {
        float* dst = dest + (size_t)blockIdx.x * CH_ELEMS;   // private slab
        for (int e = threadIdx.x; e < nvalid; e += BLOCK) dst[e] = sm[e];
    } else {
        float* dst = dest + (size_t)c0 * 4;
        for (int e = threadIdx.x; e < nvalid; e += BLOCK) atomicAdd(dst + e, sm[e]);
    }
}

template<int CH_ELEMS>
__global__ __launch_bounds__(256) void chunk_reduce(
    const float* __restrict__ ws, float* __restrict__ out, int total)
{
    int g = blockIdx.x * blockDim.x + threadIdx.x;
    if (g >= total) return;
    int c     = g / CH_ELEMS;            // CH_ELEMS is a power of two -> shift
    int local = g - c * CH_ELEMS;
    const float* p = ws + ((size_t)c * NSLICES) * CH_ELEMS + local;
    float acc = 0.f;
#pragma unroll
    for (int s = 0; s < NSLICES; ++s) acc += p[(size_t)s * CH_ELEMS];
    out[g] = acc;
}

extern "C" void kernel_launch(void* const* d_in, const int* in_sizes, int n_in,
                              void* d_out, int out_size, void* d_ws, size_t ws_size,
                              hipStream_t stream) {
    const float4* charges = (const float4*)d_in[0];
    const int2*   idx     = (const int2*)  d_in[1];
    const float*  dist    = (const float*) d_in[2];
    float*        out     = (float*)d_out;

    const int natoms = in_sizes[0] / 4;     // 200000
    const int npairs = in_sizes[2];         // 8000000
    const int total  = out_size;            // 800000

    // Can we use 128 KiB LDS per workgroup?
    int dev = 0;
    hipGetDevice(&dev);
    int maxShm = 0;
    hipDeviceGetAttribute(&maxShm, hipDeviceAttributeMaxSharedMemoryPerBlock, dev);
    const bool big = (maxShm >= 131072);

    if (big) {
        constexpr int CA = 8192, CE = CA * 4;
        const int C = (natoms + CA - 1) / CA;          // 25
        const int grid = C * NSLICES;                  // 250
        const size_t ws_need = (size_t)grid * CE * sizeof(float);  // ~32.8 MB
        if (ws_size >= ws_need) {
            hipFuncSetAttribute((const void*)chunk_scan<CA, true>,
                                hipFuncAttributeMaxDynamicSharedMemorySize, CE * 4);
            chunk_scan<CA, true><<<grid, BLOCK, CE * 4, stream>>>(
                charges, idx, dist, (float*)d_ws, npairs, natoms);
            chunk_reduce<CE><<<(total + 255) / 256, 256, 0, stream>>>(
                (const float*)d_ws, out, total);
        } else {
            hipMemsetAsync(d_out, 0, (size_t)total * sizeof(float), stream);
            hipFuncSetAttribute((const void*)chunk_scan<CA, false>,
                                hipFuncAttributeMaxDynamicSharedMemorySize, CE * 4);
            chunk_scan<CA, false><<<grid, BLOCK, CE * 4, stream>>>(
                charges, idx, dist, out, npairs, natoms);
        }
    } else {
        constexpr int CA = 4096, CE = CA * 4;
        const int C = (natoms + CA - 1) / CA;          // 49
        const int grid = C * NSLICES;                  // 490
        const size_t ws_need = (size_t)grid * CE * sizeof(float);  // ~32.1 MB
        if (ws_size >= ws_need) {
            chunk_scan<CA, true><<<grid, BLOCK, CE * 4, stream>>>(
                charges, idx, dist, (float*)d_ws, npairs, natoms);
            chunk_reduce<CE><<<(total + 255) / 256, 256, 0, stream>>>(
                (const float*)d_ws, out, total);
        } else {
            hipMemsetAsync(d_out, 0, (size_t)total * sizeof(float), stream);
            chunk_scan<CA, false><<<grid, BLOCK, CE * 4, stream>>>(
                charges, idx, dist, out, npairs, natoms);
        }
    }
}

// Round 3
// 699.005 us; speedup vs baseline: 4.6085x; 1.5330x over previous
//
#include <hip/hip_runtime.h>

// LDS-privatized chunk scatter, round 3: batch-prefetch the pair stream.
//
// R2 finding: scan loop is LATENCY-bound (VALUBusy 17.8%, HBM 4.5%, occ 45%).
// idx[] is 64 MB -> misses per-XCD L2, L3-hit latency ~500+cyc sits in a
// dependent chain with only 4 waves/SIMD (128 KiB LDS = 1 block/CU).
// Fix: unroll-and-prefetch U=8 -> 8 independent idx+dist loads in flight
// per wave before the branchy accumulate phase. dist prefetched
// unconditionally (contiguous; redundancy L3-absorbed).

#define BLOCK 1024
#define NSLICES 10
#define UNROLL 8

template<int CHUNK_ATOMS, bool USE_WS>
__global__ __launch_bounds__(BLOCK) void chunk_scan(
    const float4* __restrict__ charges,   // [natoms]
    const int2*   __restrict__ idx,       // [npairs]
    const float*  __restrict__ dist,      // [npairs]
    float*        __restrict__ dest,      // ws (slabs) or out
    int npairs, int natoms)
{
    constexpr int CH_ELEMS = CHUNK_ATOMS * 4;
    extern __shared__ float sm[];

    const int c  = blockIdx.x / NSLICES;
    const int s  = blockIdx.x - c * NSLICES;
    const int c0 = c * CHUNK_ATOMS;
    const int cn = min(CHUNK_ATOMS, natoms - c0);   // atoms in this chunk

    for (int e = threadIdx.x; e < CH_ELEMS; e += BLOCK) sm[e] = 0.f;
    __syncthreads();

    const int p0 = (int)((long long)npairs * s       / NSLICES);
    const int p1 = (int)((long long)npairs * (s + 1) / NSLICES);
    const int count  = p1 - p0;
    const int nbatch = count / (BLOCK * UNROLL);

    int p = p0 + threadIdx.x;

    for (int b = 0; b < nbatch; ++b, p += BLOCK * UNROLL) {
        int2  ij[UNROLL];
        float dd[UNROLL];
        // Phase 1: independent loads, all in flight together.
#pragma unroll
        for (int u = 0; u < UNROLL; ++u) {
            ij[u] = idx[p + u * BLOCK];
            dd[u] = dist[p + u * BLOCK];
        }
        // Phase 2: branchy accumulate (no loop-carried deps between u's).
#pragma unroll
        for (int u = 0; u < UNROLL; ++u) {
            unsigned li = (unsigned)(ij[u].x - c0);
            unsigned lj = (unsigned)(ij[u].y - c0);
            float w = 0.5f / dd[u];
            if (li < (unsigned)cn) {
                float4 cq = charges[ij[u].y];
                float* bp = sm + li * 4;
                atomicAdd(bp + 0, cq.x * w);
                atomicAdd(bp + 1, cq.y * w);
                atomicAdd(bp + 2, cq.z * w);
                atomicAdd(bp + 3, cq.w * w);
            }
            if (lj < (unsigned)cn) {
                float4 cq = charges[ij[u].x];
                float* bp = sm + lj * 4;
                atomicAdd(bp + 0, cq.x * w);
                atomicAdd(bp + 1, cq.y * w);
                atomicAdd(bp + 2, cq.z * w);
                atomicAdd(bp + 3, cq.w * w);
            }
        }
    }
    // Tail
    for (; p < p1; p += BLOCK) {
        int2 ij = idx[p];
        unsigned li = (unsigned)(ij.x - c0);
        unsigned lj = (unsigned)(ij.y - c0);
        if (li < (unsigned)cn || lj < (unsigned)cn) {
            float w = 0.5f / dist[p];
            if (li < (unsigned)cn) {
                float4 cq = charges[ij.y];
                float* bp = sm + li * 4;
                atomicAdd(bp + 0, cq.x * w);
                atomicAdd(bp + 1, cq.y * w);
                atomicAdd(bp + 2, cq.z * w);
                atomicAdd(bp + 3, cq.w * w);
            }
            if (lj < (unsigned)cn) {
                float4 cq = charges[ij.x];
                float* bp = sm + lj * 4;
                atomicAdd(bp + 0, cq.x * w);
                atomicAdd(bp + 1, cq.y * w);
                atomicAdd(bp + 2, cq.z * w);
                atomicAdd(bp + 3, cq.w * w);
            }
        }
    }
    __syncthreads();

    const int nvalid = cn * 4;
    if (USE_WS) {
        float* dst = dest + (size_t)blockIdx.x * CH_ELEMS;   // private slab
        for (int e = threadIdx.x; e < nvalid; e += BLOCK) dst[e] = sm[e];
    } else {
        float* dst = dest + (size_t)c0 * 4;
        for (int e = threadIdx.x; e < nvalid; e += BLOCK) atomicAdd(dst + e, sm[e]);
    }
}

template<int CH_ELEMS>
__global__ __launch_bounds__(256) void chunk_reduce(
    const float* __restrict__ ws, float* __restrict__ out, int total)
{
    int g = blockIdx.x * blockDim.x + threadIdx.x;
    if (g >= total) return;
    int c     = g / CH_ELEMS;
    int local = g - c * CH_ELEMS;
    const float* p = ws + ((size_t)c * NSLICES) * CH_ELEMS + local;
    float acc = 0.f;
#pragma unroll
    for (int s = 0; s < NSLICES; ++s) acc += p[(size_t)s * CH_ELEMS];
    out[g] = acc;
}

extern "C" void kernel_launch(void* const* d_in, const int* in_sizes, int n_in,
                              void* d_out, int out_size, void* d_ws, size_t ws_size,
                              hipStream_t stream) {
    const float4* charges = (const float4*)d_in[0];
    const int2*   idx     = (const int2*)  d_in[1];
    const float*  dist    = (const float*) d_in[2];
    float*        out     = (float*)d_out;

    const int natoms = in_sizes[0] / 4;     // 200000
    const int npairs = in_sizes[2];         // 8000000
    const int total  = out_size;            // 800000

    int dev = 0;
    hipGetDevice(&dev);
    int maxShm = 0;
    hipDeviceGetAttribute(&maxShm, hipDeviceAttributeMaxSharedMemoryPerBlock, dev);
    const bool big = (maxShm >= 131072);

    if (big) {
        constexpr int CA = 8192, CE = CA * 4;
        const int C = (natoms + CA - 1) / CA;          // 25
        const int grid = C * NSLICES;                  // 250
        const size_t ws_need = (size_t)grid * CE * sizeof(float);  // ~32.8 MB
        if (ws_size >= ws_need) {
            hipFuncSetAttribute((const void*)chunk_scan<CA, true>,
                                hipFuncAttributeMaxDynamicSharedMemorySize, CE * 4);
            chunk_scan<CA, true><<<grid, BLOCK, CE * 4, stream>>>(
                charges, idx, dist, (float*)d_ws, npairs, natoms);
            chunk_reduce<CE><<<(total + 255) / 256, 256, 0, stream>>>(
                (const float*)d_ws, out, total);
        } else {
            hipMemsetAsync(d_out, 0, (size_t)total * sizeof(float), stream);
            hipFuncSetAttribute((const void*)chunk_scan<CA, false>,
                                hipFuncAttributeMaxDynamicSharedMemorySize, CE * 4);
            chunk_scan<CA, false><<<grid, BLOCK, CE * 4, stream>>>(
                charges, idx, dist, out, npairs, natoms);
        }
    } else {
        constexpr int CA = 4096, CE = CA * 4;
        const int C = (natoms + CA - 1) / CA;          // 49
        const int grid = C * NSLICES;                  // 490
        const size_t ws_need = (size_t)grid * CE * sizeof(float);  // ~32.1 MB
        if (ws_size >= ws_need) {
            chunk_scan<CA, true><<<grid, BLOCK, CE * 4, stream>>>(
                charges, idx, dist, (float*)d_ws, npairs, natoms);
            chunk_reduce<CE><<<(total + 255) / 256, 256, 0, stream>>>(
                (const float*)d_ws, out, total);
        } else {
            hipMemsetAsync(d_out, 0, (size_t)total * sizeof(float), stream);
            chunk_scan<CA, false><<<grid, BLOCK, CE * 4, stream>>>(
                charges, idx, dist, out, npairs, natoms);
        }
    }
}

// Round 4
// 595.107 us; speedup vs baseline: 5.4130x; 1.1746x over previous
//
#include <hip/hip_runtime.h>

// Round 4: two-pass binning removes the 25x redundant pair-scan.
//   R3 finding: scan streamed 2.4 GB through L3 at ~3.9 TB/s, latency-bound
//   (VALUBusy 29.5%, HBM 9%). Structural fix: counting-sort pair entries by
//   destination chunk, then each chunk-block reads only its own entries.
// Entry = (other_idx | local<<18 : u32, w : f32)  [natoms<2^18, local<2^13]
// ws layout: [counts 25 | offsets 26 | cursors 25 (first 1 KiB, memset 0)]
//            [entries 2*npairs*8 B][slabs C*NSLICES*128 KiB]
// Fallback: if ws too small / LDS capped, run the R3 redundant-scan path.

#define BLOCK 1024
#define NSLICES 10
#define UNROLL 8
#define CT_BLOCK 256
#define SC_BLOCK 256
#define SC_PPT 4          // pairs per thread in scatter
#define CA_BITS 13        // chunk = 8192 atoms

// ---------------- Pass 0: count entries per bucket ----------------
__global__ __launch_bounds__(CT_BLOCK) void bucket_count(
    const int2* __restrict__ idx, unsigned* __restrict__ counts,
    int npairs, int nbuckets)
{
    __shared__ unsigned hist[32];
    for (int b = threadIdx.x; b < nbuckets; b += CT_BLOCK) hist[b] = 0;
    __syncthreads();
    const int stride = gridDim.x * CT_BLOCK;
    for (int p = blockIdx.x * CT_BLOCK + threadIdx.x; p < npairs; p += stride) {
        int2 ij = idx[p];
        atomicAdd(&hist[(unsigned)ij.x >> CA_BITS], 1u);
        atomicAdd(&hist[(unsigned)ij.y >> CA_BITS], 1u);
    }
    __syncthreads();
    for (int b = threadIdx.x; b < nbuckets; b += CT_BLOCK)
        if (hist[b]) atomicAdd(&counts[b], hist[b]);
}

// ---------------- prefix sum (25 elements) ----------------
__global__ void bucket_prefix(const unsigned* __restrict__ counts,
                              unsigned* __restrict__ offsets,
                              unsigned* __restrict__ cursors, int nbuckets)
{
    if (threadIdx.x == 0 && blockIdx.x == 0) {
        unsigned acc = 0;
        for (int b = 0; b < nbuckets; ++b) {
            offsets[b] = acc; cursors[b] = acc; acc += counts[b];
        }
        offsets[nbuckets] = acc;
    }
}

// ---------------- Pass A: scatter entries into bucket regions ----------------
__global__ __launch_bounds__(SC_BLOCK) void bucket_scatter(
    const int2*  __restrict__ idx, const float* __restrict__ dist,
    uint2* __restrict__ entries, unsigned* __restrict__ cursors,
    int npairs, int nbuckets)
{
    __shared__ unsigned hist[32];
    __shared__ unsigned base[32];
    for (int b = threadIdx.x; b < nbuckets; b += SC_BLOCK) hist[b] = 0;
    __syncthreads();

    const int p0 = blockIdx.x * (SC_BLOCK * SC_PPT) + threadIdx.x;
    unsigned key[2 * SC_PPT], bkt[2 * SC_PPT], rnk[2 * SC_PPT];
    float    wv[SC_PPT];

#pragma unroll
    for (int k = 0; k < SC_PPT; ++k) {
        int p = p0 + k * SC_BLOCK;
        if (p < npairs) {
            int2 ij = idx[p];
            wv[k] = 0.5f / dist[p];
            unsigned bi = (unsigned)ij.x >> CA_BITS;
            unsigned bj = (unsigned)ij.y >> CA_BITS;
            key[2 * k]     = (unsigned)ij.y | (((unsigned)ij.x & ((1u << CA_BITS) - 1)) << 18);
            bkt[2 * k]     = bi;
            rnk[2 * k]     = atomicAdd(&hist[bi], 1u);
            key[2 * k + 1] = (unsigned)ij.x | (((unsigned)ij.y & ((1u << CA_BITS) - 1)) << 18);
            bkt[2 * k + 1] = bj;
            rnk[2 * k + 1] = atomicAdd(&hist[bj], 1u);
        } else {
            bkt[2 * k] = bkt[2 * k + 1] = 0xFFFFFFFFu;
        }
    }
    __syncthreads();
    for (int b = threadIdx.x; b < nbuckets; b += SC_BLOCK)
        base[b] = hist[b] ? atomicAdd(&cursors[b], hist[b]) : 0u;
    __syncthreads();

#pragma unroll
    for (int k = 0; k < SC_PPT; ++k) {
        if (bkt[2 * k] != 0xFFFFFFFFu) {
            unsigned wbits = __float_as_uint(wv[k]);
            entries[base[bkt[2 * k]]     + rnk[2 * k]]     = make_uint2(key[2 * k],     wbits);
            entries[base[bkt[2 * k + 1]] + rnk[2 * k + 1]] = make_uint2(key[2 * k + 1], wbits);
        }
    }
}

// ---------------- Pass B: per-chunk LDS accumulate (no wasted scans) --------
template<int CHUNK_ATOMS>
__global__ __launch_bounds__(BLOCK) void bucket_scan(
    const float4* __restrict__ charges, const uint2* __restrict__ entries,
    const unsigned* __restrict__ offsets, float* __restrict__ slabs,
    int natoms)
{
    constexpr int CH_ELEMS = CHUNK_ATOMS * 4;
    extern __shared__ float sm[];

    const int c  = blockIdx.x / NSLICES;
    const int s  = blockIdx.x - c * NSLICES;
    for (int e = threadIdx.x; e < CH_ELEMS; e += BLOCK) sm[e] = 0.f;
    __syncthreads();

    const unsigned beg = offsets[c];
    const unsigned cnt = offsets[c + 1] - beg;
    const unsigned e0  = beg + (unsigned)((unsigned long long)cnt * s       / NSLICES);
    const unsigned e1  = beg + (unsigned)((unsigned long long)cnt * (s + 1) / NSLICES);

    unsigned e = e0 + threadIdx.x;
    const unsigned nb = (e1 > e0) ? (e1 - e0) / (BLOCK * 4) : 0;
    for (unsigned b = 0; b < nb; ++b, e += BLOCK * 4) {
        uint2 en[4];
#pragma unroll
        for (int u = 0; u < 4; ++u) en[u] = entries[e + u * BLOCK];
        float4 cq[4];
#pragma unroll
        for (int u = 0; u < 4; ++u) cq[u] = charges[en[u].x & 0x3FFFFu];
#pragma unroll
        for (int u = 0; u < 4; ++u) {
            float w = __uint_as_float(en[u].y);
            float* bp = sm + (en[u].x >> 18) * 4;
            atomicAdd(bp + 0, cq[u].x * w);
            atomicAdd(bp + 1, cq[u].y * w);
            atomicAdd(bp + 2, cq[u].z * w);
            atomicAdd(bp + 3, cq[u].w * w);
        }
    }
    for (; e < e1; e += BLOCK) {
        uint2 en = entries[e];
        float4 cq = charges[en.x & 0x3FFFFu];
        float w = __uint_as_float(en.y);
        float* bp = sm + (en.x >> 18) * 4;
        atomicAdd(bp + 0, cq.x * w);
        atomicAdd(bp + 1, cq.y * w);
        atomicAdd(bp + 2, cq.z * w);
        atomicAdd(bp + 3, cq.w * w);
    }
    __syncthreads();

    const int c0 = c * CHUNK_ATOMS;
    const int nvalid = min(CHUNK_ATOMS, natoms - c0) * 4;
    float* dst = slabs + (size_t)blockIdx.x * CH_ELEMS;
    for (int e2 = threadIdx.x; e2 < nvalid; e2 += BLOCK) dst[e2] = sm[e2];
}

// ---------------- slab reduce ----------------
template<int CH_ELEMS>
__global__ __launch_bounds__(256) void chunk_reduce(
    const float* __restrict__ ws, float* __restrict__ out, int total)
{
    int g = blockIdx.x * blockDim.x + threadIdx.x;
    if (g >= total) return;
    int c     = g / CH_ELEMS;
    int local = g - c * CH_ELEMS;
    const float* p = ws + ((size_t)c * NSLICES) * CH_ELEMS + local;
    float acc = 0.f;
#pragma unroll
    for (int s = 0; s < NSLICES; ++s) acc += p[(size_t)s * CH_ELEMS];
    out[g] = acc;
}

// ---------------- R3 fallback: redundant chunk scan ----------------
template<int CHUNK_ATOMS, bool USE_WS>
__global__ __launch_bounds__(BLOCK) void chunk_scan(
    const float4* __restrict__ charges, const int2* __restrict__ idx,
    const float* __restrict__ dist, float* __restrict__ dest,
    int npairs, int natoms)
{
    constexpr int CH_ELEMS = CHUNK_ATOMS * 4;
    extern __shared__ float sm[];
    const int c  = blockIdx.x / NSLICES;
    const int s  = blockIdx.x - c * NSLICES;
    const int c0 = c * CHUNK_ATOMS;
    const int cn = min(CHUNK_ATOMS, natoms - c0);
    for (int e = threadIdx.x; e < CH_ELEMS; e += BLOCK) sm[e] = 0.f;
    __syncthreads();
    const int p0 = (int)((long long)npairs * s       / NSLICES);
    const int p1 = (int)((long long)npairs * (s + 1) / NSLICES);
    const int nbatch = (p1 - p0) / (BLOCK * UNROLL);
    int p = p0 + threadIdx.x;
    for (int b = 0; b < nbatch; ++b, p += BLOCK * UNROLL) {
        int2 ij[UNROLL]; float dd[UNROLL];
#pragma unroll
        for (int u = 0; u < UNROLL; ++u) { ij[u] = idx[p + u * BLOCK]; dd[u] = dist[p + u * BLOCK]; }
#pragma unroll
        for (int u = 0; u < UNROLL; ++u) {
            unsigned li = (unsigned)(ij[u].x - c0), lj = (unsigned)(ij[u].y - c0);
            float w = 0.5f / dd[u];
            if (li < (unsigned)cn) {
                float4 cq = charges[ij[u].y]; float* bp = sm + li * 4;
                atomicAdd(bp + 0, cq.x * w); atomicAdd(bp + 1, cq.y * w);
                atomicAdd(bp + 2, cq.z * w); atomicAdd(bp + 3, cq.w * w);
            }
            if (lj < (unsigned)cn) {
                float4 cq = charges[ij[u].x]; float* bp = sm + lj * 4;
                atomicAdd(bp + 0, cq.x * w); atomicAdd(bp + 1, cq.y * w);
                atomicAdd(bp + 2, cq.z * w); atomicAdd(bp + 3, cq.w * w);
            }
        }
    }
    for (; p < p1; p += BLOCK) {
        int2 ij = idx[p];
        unsigned li = (unsigned)(ij.x - c0), lj = (unsigned)(ij.y - c0);
        if (li < (unsigned)cn || lj < (unsigned)cn) {
            float w = 0.5f / dist[p];
            if (li < (unsigned)cn) {
                float4 cq = charges[ij.y]; float* bp = sm + li * 4;
                atomicAdd(bp + 0, cq.x * w); atomicAdd(bp + 1, cq.y * w);
                atomicAdd(bp + 2, cq.z * w); atomicAdd(bp + 3, cq.w * w);
            }
            if (lj < (unsigned)cn) {
                float4 cq = charges[ij.x]; float* bp = sm + lj * 4;
                atomicAdd(bp + 0, cq.x * w); atomicAdd(bp + 1, cq.y * w);
                atomicAdd(bp + 2, cq.z * w); atomicAdd(bp + 3, cq.w * w);
            }
        }
    }
    __syncthreads();
    const int nvalid = cn * 4;
    if (USE_WS) {
        float* dst = dest + (size_t)blockIdx.x * CH_ELEMS;
        for (int e = threadIdx.x; e < nvalid; e += BLOCK) dst[e] = sm[e];
    } else {
        float* dst = dest + (size_t)c0 * 4;
        for (int e = threadIdx.x; e < nvalid; e += BLOCK) atomicAdd(dst + e, sm[e]);
    }
}

extern "C" void kernel_launch(void* const* d_in, const int* in_sizes, int n_in,
                              void* d_out, int out_size, void* d_ws, size_t ws_size,
                              hipStream_t stream) {
    const float4* charges = (const float4*)d_in[0];
    const int2*   idx     = (const int2*)  d_in[1];
    const float*  dist    = (const float*) d_in[2];
    float*        out     = (float*)d_out;

    const int natoms = in_sizes[0] / 4;     // 200000
    const int npairs = in_sizes[2];         // 8000000
    const int total  = out_size;            // 800000

    int dev = 0;
    hipGetDevice(&dev);
    int maxShm = 0;
    hipDeviceGetAttribute(&maxShm, hipDeviceAttributeMaxSharedMemoryPerBlock, dev);
    const bool big = (maxShm >= 131072);

    constexpr int CA = 8192, CE = CA * 4;
    const int C    = (natoms + CA - 1) / CA;       // 25
    const int grid = C * NSLICES;                  // 250

    // ws layout for the binning path
    const size_t ENT_OFF    = 1024;
    const size_t ent_bytes  = (size_t)2 * npairs * sizeof(uint2);  // 128 MB
    size_t slab_off         = (ENT_OFF + ent_bytes + 255) & ~(size_t)255;
    const size_t slab_bytes = (size_t)grid * CE * sizeof(float);   // 32.8 MB
    const size_t need       = slab_off + slab_bytes;

    if (big && ws_size >= need && natoms <= (1 << 18)) {
        unsigned* counts  = (unsigned*)d_ws;               // [25]
        unsigned* offsets = (unsigned*)((char*)d_ws + 256);// [26]
        unsigned* cursors = (unsigned*)((char*)d_ws + 512);// [25]
        uint2*    entries = (uint2*)((char*)d_ws + ENT_OFF);
        float*    slabs   = (float*)((char*)d_ws + slab_off);

        hipMemsetAsync(d_ws, 0, 1024, stream);
        bucket_count<<<2048, CT_BLOCK, 0, stream>>>(idx, counts, npairs, C);
        bucket_prefix<<<1, 32, 0, stream>>>(counts, offsets, cursors, C);
        const int sc_grid = (npairs + SC_BLOCK * SC_PPT - 1) / (SC_BLOCK * SC_PPT);
        bucket_scatter<<<sc_grid, SC_BLOCK, 0, stream>>>(idx, dist, entries, cursors, npairs, C);
        hipFuncSetAttribute((const void*)bucket_scan<CA>,
                            hipFuncAttributeMaxDynamicSharedMemorySize, CE * 4);
        bucket_scan<CA><<<grid, BLOCK, CE * 4, stream>>>(charges, entries, offsets, slabs, natoms);
        chunk_reduce<CE><<<(total + 255) / 256, 256, 0, stream>>>(slabs, out, total);
    } else if (big) {
        const size_t ws_need = (size_t)grid * CE * sizeof(float);
        if (ws_size >= ws_need) {
            hipFuncSetAttribute((const void*)chunk_scan<CA, true>,
                                hipFuncAttributeMaxDynamicSharedMemorySize, CE * 4);
            chunk_scan<CA, true><<<grid, BLOCK, CE * 4, stream>>>(
                charges, idx, dist, (float*)d_ws, npairs, natoms);
            chunk_reduce<CE><<<(total + 255) / 256, 256, 0, stream>>>(
                (const float*)d_ws, out, total);
        } else {
            hipMemsetAsync(d_out, 0, (size_t)total * sizeof(float), stream);
            hipFuncSetAttribute((const void*)chunk_scan<CA, false>,
                                hipFuncAttributeMaxDynamicSharedMemorySize, CE * 4);
            chunk_scan<CA, false><<<grid, BLOCK, CE * 4, stream>>>(
                charges, idx, dist, out, npairs, natoms);
        }
    } else {
        constexpr int CA2 = 4096, CE2 = CA2 * 4;
        const int C2 = (natoms + CA2 - 1) / CA2;
        const int grid2 = C2 * NSLICES;
        const size_t ws_need = (size_t)grid2 * CE2 * sizeof(float);
        if (ws_size >= ws_need) {
            chunk_scan<CA2, true><<<grid2, BLOCK, CE2 * 4, stream>>>(
                charges, idx, dist, (float*)d_ws, npairs, natoms);
            chunk_reduce<CE2><<<(total + 255) / 256, 256, 0, stream>>>(
                (const float*)d_ws, out, total);
        } else {
            hipMemsetAsync(d_out, 0, (size_t)total * sizeof(float), stream);
            chunk_scan<CA2, false><<<grid2, BLOCK, CE2 * 4, stream>>>(
                charges, idx, dist, out, npairs, natoms);
        }
    }
}